// Round 18
// baseline (363.326 us; speedup 1.0000x reference)
//
#include <hip/hip_runtime.h>
#include <hip/hip_bf16.h>
#include <stdint.h>

// MoE top-1. Round 18: r17 GEMMs FROZEN (best: 356us, blocked-A layouts);
// prep chain fused 7->4 kernels: {scan+fill} one block, {mkperm+gather+initout}
// one per-token kernel. Removes 3 launches + dependency gaps.
#define N_TOK 4096
#define DIM   768
#define NE    8
#define HDIM  7680
#define ODIM  768
#define G1GRID 2816
#define G2GRID 1344
#define KC1 96            // DIM/8 k-chunks
#define KC2 960           // HDIM/8 k-chunks
#define XB1 (KC1 * 128)   // ushorts per 16-slot block of Xg (12288)
#define XB2 (KC2 * 128)   // ushorts per 16-slot block of H (122880)
#define NSLOT 5120        // padded slot space

typedef __bf16 bf16x8 __attribute__((ext_vector_type(8)));
typedef float f32x4 __attribute__((ext_vector_type(4)));

__device__ __forceinline__ unsigned short f2bf(float f) {
    union { float f; unsigned u; } v; v.f = f;
    return (unsigned short)((v.u + 0x7fffu + ((v.u >> 16) & 1u)) >> 16);
}

__device__ __forceinline__ unsigned cvt_pk_bf16(float lo, float hi) {
    unsigned r;
    asm("v_cvt_pk_bf16_f32 %0, %1, %2" : "=v"(r) : "v"(lo), "v"(hi));
    return r;
}

__device__ __forceinline__ void gload_lds16(const unsigned short* g, unsigned short* l) {
    __builtin_amdgcn_global_load_lds(
        (const __attribute__((address_space(1))) unsigned int*)g,
        (__attribute__((address_space(3))) unsigned int*)l, 16, 0, 0);
}

// ---------------- gating (validated r1-r17) ----------------
__global__ void moe_gating(const float* __restrict__ x, const float* __restrict__ Wg,
                           const float* __restrict__ bg, int* __restrict__ cnt,
                           int* __restrict__ top_e, int* __restrict__ rnk,
                           float* __restrict__ top_p) {
    const int wid  = threadIdx.x >> 6;
    const int lane = threadIdx.x & 63;
    const int t = blockIdx.x * 4 + wid;
    double p[NE];
#pragma unroll
    for (int j = 0; j < NE; ++j) p[j] = 0.0;
    const float* xr  = x  + (size_t)t * DIM + lane * 12;
    const float* wr0 = Wg + lane * 12 * NE;
#pragma unroll
    for (int i = 0; i < 12; ++i) {
        double xv = (double)xr[i];
#pragma unroll
        for (int j = 0; j < NE; ++j) p[j] += xv * (double)wr0[i * NE + j];
    }
#pragma unroll
    for (int off = 32; off >= 1; off >>= 1)
#pragma unroll
        for (int j = 0; j < NE; ++j) p[j] += __shfl_xor(p[j], off, 64);
    if (lane == 0) {
        double l[NE];
#pragma unroll
        for (int j = 0; j < NE; ++j) l[j] = p[j] + (double)bg[j];
        int be = 0; double bl = l[0];
#pragma unroll
        for (int j = 1; j < NE; ++j) if (l[j] > bl) { bl = l[j]; be = j; }
        double s = 0.0;
#pragma unroll
        for (int j = 0; j < NE; ++j) s += exp(l[j] - bl);
        int rk = atomicAdd(&cnt[be], 1);
        top_e[t] = be; rnk[t] = rk; top_p[t] = (float)(1.0 / s);
    }
}

__global__ void moe_init(int* cnt) { if (threadIdx.x < NE) cnt[threadIdx.x] = 0; }

// FUSED scan+fill: one block, 256 threads. Phase 1: offs (128-padded), mc,
// per-XCD group starts. Phase 2: fill both dispatch tables.
__global__ void moe_scanfill(const int* __restrict__ cnt, int* __restrict__ offs,
                             int* __restrict__ tbl1, int* __restrict__ tbl2) {
    __shared__ int smc[NE];
    __shared__ int sg1[480], sg2[48];
    int tid = threadIdx.x;
    if (tid == 0) {
        int s = 0;
        for (int e = 0; e < NE; ++e) { offs[e] = s; s += (cnt[e] + 127) & ~127; }
    }
    if (tid < NE) smc[tid] = (cnt[tid] + 127) >> 7;
    __syncthreads();
    if (tid < 8) {
        int s = 0;
        for (int j = 0; j < 60; ++j) { int p = tid + 8 * j; sg1[p] = s; s += smc[p / 60]; }
        int s2 = 0;
        for (int j = 0; j < 6; ++j)  { int p = tid + 8 * j; sg2[p] = s2; s2 += 4 * smc[p / 6]; }
    }
    __syncthreads();
    for (int gid = tid; gid < G1GRID + G2GRID; gid += 256) {
        if (gid < G1GRID) {
            int c = gid & 7, slot = gid >> 3;
            int sel = c;
            for (int j = 0; j < 60; ++j) { int p = c + 8 * j; if (sg1[p] <= slot) sel = p; else break; }
            int e = sel / 60, n0 = sel % 60;
            int mt = slot - sg1[sel];
            tbl1[gid] = (mt < smc[e]) ? ((e << 14) | (mt << 8) | (n0 << 2)) : -1;
        } else {
            int gg = gid - G1GRID;
            int c = gg & 7, slot = gg >> 3;
            int sel = c;
            for (int j = 0; j < 6; ++j) { int p = c + 8 * j; if (sg2[p] <= slot) sel = p; else break; }
            int e = sel / 6, n0 = sel % 6;
            int mem = slot - sg2[sel];
            int mcE = smc[e];
            int ks = mem / mcE, mt = mem - ks * mcE;
            tbl2[gg] = (mem < 4 * mcE) ? ((e << 14) | (mt << 8) | (n0 << 2) | ks) : -1;
        }
    }
}

// FUSED mkperm + gather + initout: one block per token, 256 threads.
// Writes perm/gate_s, converts x row into blocked Xg, seeds out = gate*b2[e].
__global__ void moe_permgather(const float* __restrict__ x, const int* __restrict__ top_e,
                               const int* __restrict__ rnk, const float* __restrict__ top_p,
                               const int* __restrict__ offs, int* __restrict__ perm,
                               float* __restrict__ gate_s, unsigned short* __restrict__ Xg,
                               const float* __restrict__ b2, float* __restrict__ out) {
    int t = blockIdx.x;
    int e = top_e[t];
    int slot = offs[e] + rnk[t];
    float gv = top_p[t];
    int tid = threadIdx.x;
    if (tid == 0) { perm[slot] = t; gate_s[slot] = gv; }
    if (tid < KC1) {   // blocked gather: 96 chunks of 8
        const float* s8 = x + (size_t)t * DIM + tid * 8;
        union { uint4 q; unsigned short u[8]; } v;
#pragma unroll
        for (int j = 0; j < 8; ++j) v.u[j] = f2bf(s8[j]);
        *(uint4*)&Xg[(size_t)(slot >> 4) * XB1 + tid * 128 + (slot & 15) * 8] = v.q;
    }
    // initout: 768 cols over 256 threads x 3
    const float* b = b2 + (size_t)e * ODIM;
    float* o = out + (size_t)t * ODIM;
#pragma unroll
    for (int i = 0; i < 3; ++i) o[tid + i * 256] = gv * b[tid + i * 256];
}

// ---------------- grouped GEMM (byte-identical to r17) ----------------
template<int LAYER>
__global__ __launch_bounds__(256, 3) void moe_gemm(
    const unsigned short* __restrict__ A, const float* __restrict__ B,
    const float* __restrict__ bias, const int* __restrict__ cnt,
    const int* __restrict__ offs, const int* __restrict__ perm,
    const float* __restrict__ gate_s, const int* __restrict__ tbl,
    unsigned short* __restrict__ H, float* __restrict__ out) {

    constexpr int NT    = (LAYER == 1) ? HDIM : ODIM;
    constexpr int ABLK  = (LAYER == 1) ? XB1  : XB2;
    constexpr int KFULL = (LAYER == 1) ? DIM  : HDIM;
    constexpr int KBLK  = (LAYER == 1) ? DIM  : HDIM / 4;
    constexpr int NITER = KBLK / 32;

    const int code = tbl[blockIdx.x];
    if (code < 0) return;
    const int e  = code >> 14;
    const int mt = (code >> 8) & 63;
    const int n0 = ((code >> 2) & 63) * 128;
    const int ks = code & 3;
    const int ne = cnt[e];
    const int base = offs[e];
    const int kbase = ks * KBLK;

    __shared__ __align__(16) unsigned short As[3][4096];
    __shared__ __align__(16) unsigned short Bs[2][4096];

    const int tid = threadIdx.x;
    const int lane = tid & 63, w = tid >> 6;
    const int wr = w >> 1, wc = w & 1;
    const int g = lane >> 4, r = lane & 15;

    const int ab16 = (base + mt * 128) >> 4;
    const unsigned short* aS0 = A + (size_t)(ab16 + 2 * w) * ABLK
                                  + (size_t)(kbase >> 3) * 128 + lane * 8;
    const unsigned short* aS1 = aS0 + ABLK;
    const int aD0 = (2 * w) * 512;
    const int aD1 = aD0 + 512;

    const int bn = tid & 127;
    const int kh = tid >> 7;
    const float* bS = B + (size_t)e * KFULL * NT + (size_t)(kbase + kh * 16) * NT + n0 + bn;
    const int bD = (bn >> 4) * 512 + (kh * 2) * 128 + (bn & 15) * 8;

    f32x4 acc[4][4] = {};
    float bvA[16], bvB[16];

    unsigned short* A0 = &As[0][0];
    unsigned short* A1 = &As[1][0];
    unsigned short* A2 = &As[2][0];

#define LOADB(dst_, t_)                                                        \
    do { const float* bp_ = bS + (size_t)((t_) * 32) * NT;                     \
        _Pragma("unroll")                                                      \
        for (int i_ = 0; i_ < 16; ++i_) dst_[i_] = bp_[(size_t)i_ * NT];       \
    } while (0)

#define DMA_A(t_, abase_)                                                      \
    do { gload_lds16(aS0 + (t_) * 512, (abase_) + aD0);                        \
         gload_lds16(aS1 + (t_) * 512, (abase_) + aD1); } while (0)

#define COMMITB(src_, buf_)                                                    \
    do { uint4 q0_, q1_;                                                       \
        q0_.x = cvt_pk_bf16(src_[0],  src_[1]);  q0_.y = cvt_pk_bf16(src_[2],  src_[3]);  \
        q0_.z = cvt_pk_bf16(src_[4],  src_[5]);  q0_.w = cvt_pk_bf16(src_[6],  src_[7]);  \
        q1_.x = cvt_pk_bf16(src_[8],  src_[9]);  q1_.y = cvt_pk_bf16(src_[10], src_[11]); \
        q1_.z = cvt_pk_bf16(src_[12], src_[13]); q1_.w = cvt_pk_bf16(src_[14], src_[15]); \
        *(uint4*)&Bs[buf_][bD]       = q0_;                                    \
        *(uint4*)&Bs[buf_][bD + 128] = q1_;                                    \
    } while (0)

#define PHASE_END                                                              \
    do { asm volatile("s_waitcnt lgkmcnt(0)" ::: "memory");                    \
         __builtin_amdgcn_s_barrier();                                         \
         __builtin_amdgcn_sched_barrier(0); } while (0)

#define BODY(t_, cur_, ARD_, ADMA_, LDst_, CMsrc_, MODE_)                      \
    do {                                                                       \
        bf16x8 af_[4], bf_[4];                                                 \
        _Pragma("unroll")                                                      \
        for (int m_ = 0; m_ < 4; ++m_)                                         \
            af_[m_] = *(const bf16x8*)((ARD_) + (wr * 4 + m_) * 512 + lane * 8); \
        _Pragma("unroll")                                                      \
        for (int n_ = 0; n_ < 4; ++n_)                                         \
            bf_[n_] = *(const bf16x8*)&Bs[cur_][(wc * 4 + n_) * 512 + lane * 8]; \
        if (MODE_ == 2) DMA_A((t_) + 2, ADMA_);                                \
        if (MODE_ == 2) LOADB(LDst_, (t_) + 2);                                \
        _Pragma("unroll")                                                      \
        for (int n_ = 0; n_ < 4; ++n_)                                         \
            _Pragma("unroll")                                                  \
            for (int m_ = 0; m_ < 4; ++m_)                                     \
                acc[m_][n_] = __builtin_amdgcn_mfma_f32_16x16x32_bf16(         \
                    af_[m_], bf_[n_], acc[m_][n_], 0, 0, 0);                   \
        if (MODE_ >= 1) { COMMITB(CMsrc_, (cur_) ^ 1); PHASE_END; }            \
    } while (0)

    DMA_A(0, A0);
    LOADB(bvA, 0);
    DMA_A(1, A1);
    LOADB(bvB, 1);
    COMMITB(bvA, 0);
    PHASE_END;

#pragma unroll 1
    for (int t = 0; t + 4 <= NITER; t += 2) {
        BODY(t,     0, A0, A2, bvA, bvB, 2);
        BODY(t + 1, 1, A1, A0, bvB, bvA, 2);
        unsigned short* tr_ = A2; A2 = A1; A1 = A0; A0 = tr_;
    }
    BODY(NITER - 2, 0, A0, A2, bvA, bvB, 1);
    BODY(NITER - 1, 1, A1, A2, bvB, bvA, 0);

#undef BODY
#undef PHASE_END
#undef COMMITB
#undef DMA_A
#undef LOADB

#pragma unroll
    for (int m = 0; m < 4; ++m) {
#pragma unroll
        for (int j = 0; j < 4; ++j) {
            int lrow = mt * 128 + wr * 64 + m * 16 + g * 4 + j;
            if (lrow < ne) {
                int slot = base + lrow;
#pragma unroll
                for (int n = 0; n < 4; ++n) {
                    int col = n0 + wc * 64 + n * 16 + r;
                    if constexpr (LAYER == 1) {
                        float v = acc[m][n][j] + bias[(size_t)e * NT + col];
                        v = fmaxf(v, 0.0f);
                        H[(size_t)(slot >> 4) * XB2 + (size_t)(col >> 3) * 128
                          + (slot & 15) * 8 + (col & 7)] = f2bf(v);
                    } else {
                        atomicAdd(&out[(size_t)perm[slot] * ODIM + col],
                                  gate_s[slot] * acc[m][n][j]);
                    }
                }
            }
        }
    }
}

// ---------------- launch ----------------
extern "C" void kernel_launch(void* const* d_in, const int* in_sizes, int n_in,
                              void* d_out, int out_size, void* d_ws, size_t ws_size,
                              hipStream_t stream) {
    const float* x  = (const float*)d_in[0];
    const float* Wg = (const float*)d_in[1];
    const float* bg = (const float*)d_in[2];
    const float* W1 = (const float*)d_in[3];
    const float* b1 = (const float*)d_in[4];
    const float* W2 = (const float*)d_in[5];
    const float* b2 = (const float*)d_in[6];
    float* out = (float*)d_out;

    char* ws = (char*)d_ws;
    int*   cnt    = (int*)(ws + 0);
    int*   offs   = (int*)(ws + 64);
    int*   tbl1   = (int*)(ws + 3072);             // 2816 ints -> ends 14336
    int*   tbl2   = (int*)(ws + 14336);            // 1344 ints -> ends 19712
    int*   top_e  = (int*)(ws + 19712);            // 4096 ints
    int*   rnk    = (int*)(ws + 19712 + 16384);    // 4096 ints
    float* top_p  = (float*)(ws + 19712 + 2 * 16384);   // 4096 f32
    int*   perm   = (int*)(ws + 68864);            // NSLOT ints
    float* gate_s = (float*)(ws + 89344);          // NSLOT f32
    unsigned short* Xg = (unsigned short*)(ws + 110592);                    // 7.86MB
    unsigned short* H  = (unsigned short*)(ws + 110592 + 320ull * XB1 * 2); // 78.6MB
    // total ws ~86.6 MB

    moe_init<<<1, 64, 0, stream>>>(cnt);
    moe_gating<<<N_TOK / 4, 256, 0, stream>>>(x, Wg, bg, cnt, top_e, rnk, top_p);
    moe_scanfill<<<1, 256, 0, stream>>>(cnt, offs, tbl1, tbl2);
    moe_permgather<<<N_TOK, 256, 0, stream>>>(x, top_e, rnk, top_p, offs,
                                              perm, gate_s, Xg, b2, out);
    moe_gemm<1><<<G1GRID, 256, 0, stream>>>(Xg, W1, b1, cnt, offs, perm, gate_s, tbl1, H, out);
    moe_gemm<2><<<G2GRID, 256, 0, stream>>>(H, W2, b2, cnt, offs, perm, gate_s, tbl2, H, out);
}

// Round 19
// 357.211 us; speedup vs baseline: 1.0171x; 1.0171x over previous
//
#include <hip/hip_runtime.h>
#include <hip/hip_bf16.h>
#include <stdint.h>

// MoE top-1. Round 19: r17 (best, 356us) locked in; moe_init kernel replaced
// by hipMemsetAsync (one fewer launch). Blocked A-layouts: Xg/H stored as
// [slot/16][k/8][16][8] so each A-cell global_load_lds reads 1KB contiguous.
// GEMM K-loop: r9 unpinned depth-2 (triple-buffered A-DMA, fp32-B via regs
// + cvt_pk + ds_write), 0 bank conflicts, XCD-grouped dispatch tables.
#define N_TOK 4096
#define DIM   768
#define NE    8
#define HDIM  7680
#define ODIM  768
#define G1GRID 2816
#define G2GRID 1344
#define KC1 96            // DIM/8 k-chunks
#define KC2 960           // HDIM/8 k-chunks
#define XB1 (KC1 * 128)   // ushorts per 16-slot block of Xg (12288)
#define XB2 (KC2 * 128)   // ushorts per 16-slot block of H (122880)
#define NSLOT 5120        // padded slot space

typedef __bf16 bf16x8 __attribute__((ext_vector_type(8)));
typedef float f32x4 __attribute__((ext_vector_type(4)));

__device__ __forceinline__ unsigned short f2bf(float f) {
    union { float f; unsigned u; } v; v.f = f;
    return (unsigned short)((v.u + 0x7fffu + ((v.u >> 16) & 1u)) >> 16);
}

__device__ __forceinline__ unsigned cvt_pk_bf16(float lo, float hi) {
    unsigned r;
    asm("v_cvt_pk_bf16_f32 %0, %1, %2" : "=v"(r) : "v"(lo), "v"(hi));
    return r;
}

__device__ __forceinline__ void gload_lds16(const unsigned short* g, unsigned short* l) {
    __builtin_amdgcn_global_load_lds(
        (const __attribute__((address_space(1))) unsigned int*)g,
        (__attribute__((address_space(3))) unsigned int*)l, 16, 0, 0);
}

// ---------------- gating & prep (validated r1-r18) ----------------
__global__ void moe_gating(const float* __restrict__ x, const float* __restrict__ Wg,
                           const float* __restrict__ bg, int* __restrict__ cnt,
                           int* __restrict__ top_e, int* __restrict__ rnk,
                           float* __restrict__ top_p) {
    const int wid  = threadIdx.x >> 6;
    const int lane = threadIdx.x & 63;
    const int t = blockIdx.x * 4 + wid;
    double p[NE];
#pragma unroll
    for (int j = 0; j < NE; ++j) p[j] = 0.0;
    const float* xr  = x  + (size_t)t * DIM + lane * 12;
    const float* wr0 = Wg + lane * 12 * NE;
#pragma unroll
    for (int i = 0; i < 12; ++i) {
        double xv = (double)xr[i];
#pragma unroll
        for (int j = 0; j < NE; ++j) p[j] += xv * (double)wr0[i * NE + j];
    }
#pragma unroll
    for (int off = 32; off >= 1; off >>= 1)
#pragma unroll
        for (int j = 0; j < NE; ++j) p[j] += __shfl_xor(p[j], off, 64);
    if (lane == 0) {
        double l[NE];
#pragma unroll
        for (int j = 0; j < NE; ++j) l[j] = p[j] + (double)bg[j];
        int be = 0; double bl = l[0];
#pragma unroll
        for (int j = 1; j < NE; ++j) if (l[j] > bl) { bl = l[j]; be = j; }
        double s = 0.0;
#pragma unroll
        for (int j = 0; j < NE; ++j) s += exp(l[j] - bl);
        int rk = atomicAdd(&cnt[be], 1);
        top_e[t] = be; rnk[t] = rk; top_p[t] = (float)(1.0 / s);
    }
}

// offs[e] PADDED to 128-multiples; mc[e] = ceil(cnt/128); per-XCD group starts.
__global__ void moe_scan(const int* __restrict__ cnt, int* __restrict__ offs,
                         int* __restrict__ mc, int* __restrict__ g1s,
                         int* __restrict__ g2s) {
    __shared__ int smc[NE];
    int tid = threadIdx.x;
    if (tid == 0) {
        int s = 0;
        for (int e = 0; e < NE; ++e) { offs[e] = s; s += (cnt[e] + 127) & ~127; }
    }
    if (tid < NE) { smc[tid] = (cnt[tid] + 127) >> 7; mc[tid] = smc[tid]; }
    __syncthreads();
    if (tid < 8) {
        int s = 0;
        for (int j = 0; j < 60; ++j) { int p = tid + 8 * j; g1s[p] = s; s += smc[p / 60]; }
        int s2 = 0;
        for (int j = 0; j < 6; ++j)  { int p = tid + 8 * j; g2s[p] = s2; s2 += 4 * smc[p / 6]; }
    }
}

__global__ void moe_fill(const int* __restrict__ mc, const int* __restrict__ g1s,
                         const int* __restrict__ g2s, int* __restrict__ tbl1,
                         int* __restrict__ tbl2) {
    int gid = blockIdx.x * 256 + threadIdx.x;
    if (gid < G1GRID) {
        int c = gid & 7, slot = gid >> 3;
        int sel = c;
        for (int j = 0; j < 60; ++j) { int p = c + 8 * j; if (g1s[p] <= slot) sel = p; else break; }
        int e = sel / 60, n0 = sel % 60;
        int mt = slot - g1s[sel];
        tbl1[gid] = (mt < mc[e]) ? ((e << 14) | (mt << 8) | (n0 << 2)) : -1;
    } else if (gid < G1GRID + G2GRID) {
        int gg = gid - G1GRID;
        int c = gg & 7, slot = gg >> 3;
        int sel = c;
        for (int j = 0; j < 6; ++j) { int p = c + 8 * j; if (g2s[p] <= slot) sel = p; else break; }
        int e = sel / 6, n0 = sel % 6;
        int mem = slot - g2s[sel];
        int mcE = mc[e];
        int ks = mem / mcE, mt = mem - ks * mcE;
        tbl2[gg] = (mem < 4 * mcE) ? ((e << 14) | (mt << 8) | (n0 << 2) | ks) : -1;
    }
}

__global__ void moe_mkperm(const int* __restrict__ top_e, const int* __restrict__ rnk,
                           const float* __restrict__ top_p, const int* __restrict__ offs,
                           int* __restrict__ perm, float* __restrict__ gate_s) {
    int t = blockIdx.x * 256 + threadIdx.x;
    int e = top_e[t];
    int slot = offs[e] + rnk[t];
    perm[slot] = t;
    gate_s[slot] = top_p[t];
}

// Gather x into BLOCKED Xg: elem (slot,k) at (slot>>4)*XB1 + (k>>3)*128
// + (slot&15)*8 + (k&7). One 16B store per (token, k-chunk).
__global__ void moe_gather(const float* __restrict__ x, const int* __restrict__ top_e,
                           const int* __restrict__ rnk, const int* __restrict__ offs,
                           unsigned short* __restrict__ Xg) {
    int t = blockIdx.x;
    int slot = offs[top_e[t]] + rnk[t];
    int kc = threadIdx.x;
    if (kc < KC1) {
        const float* s8 = x + (size_t)t * DIM + kc * 8;
        union { uint4 q; unsigned short u[8]; } v;
#pragma unroll
        for (int j = 0; j < 8; ++j) v.u[j] = f2bf(s8[j]);
        *(uint4*)&Xg[(size_t)(slot >> 4) * XB1 + kc * 128 + (slot & 15) * 8] = v.q;
    }
}

__global__ void moe_initout(const int* __restrict__ top_e, const float* __restrict__ top_p,
                            const float* __restrict__ b2, float* __restrict__ out) {
    int t = blockIdx.x;
    int e = top_e[t];
    float gv = top_p[t];
    const float* b = b2 + (size_t)e * ODIM;
    float* o = out + (size_t)t * ODIM;
    for (int i = threadIdx.x; i < ODIM; i += 256) o[i] = gv * b[i];
}

// ---------------- grouped GEMM (byte-identical to r17) ----------------
template<int LAYER>
__global__ __launch_bounds__(256, 3) void moe_gemm(
    const unsigned short* __restrict__ A, const float* __restrict__ B,
    const float* __restrict__ bias, const int* __restrict__ cnt,
    const int* __restrict__ offs, const int* __restrict__ perm,
    const float* __restrict__ gate_s, const int* __restrict__ tbl,
    unsigned short* __restrict__ H, float* __restrict__ out) {

    constexpr int NT    = (LAYER == 1) ? HDIM : ODIM;
    constexpr int ABLK  = (LAYER == 1) ? XB1  : XB2;
    constexpr int KFULL = (LAYER == 1) ? DIM  : HDIM;
    constexpr int KBLK  = (LAYER == 1) ? DIM  : HDIM / 4;
    constexpr int NITER = KBLK / 32;

    const int code = tbl[blockIdx.x];
    if (code < 0) return;
    const int e  = code >> 14;
    const int mt = (code >> 8) & 63;
    const int n0 = ((code >> 2) & 63) * 128;
    const int ks = code & 3;
    const int ne = cnt[e];
    const int base = offs[e];
    const int kbase = ks * KBLK;

    __shared__ __align__(16) unsigned short As[3][4096];
    __shared__ __align__(16) unsigned short Bs[2][4096];

    const int tid = threadIdx.x;
    const int lane = tid & 63, w = tid >> 6;
    const int wr = w >> 1, wc = w & 1;
    const int g = lane >> 4, r = lane & 15;

    const int ab16 = (base + mt * 128) >> 4;
    const unsigned short* aS0 = A + (size_t)(ab16 + 2 * w) * ABLK
                                  + (size_t)(kbase >> 3) * 128 + lane * 8;
    const unsigned short* aS1 = aS0 + ABLK;
    const int aD0 = (2 * w) * 512;
    const int aD1 = aD0 + 512;

    const int bn = tid & 127;
    const int kh = tid >> 7;
    const float* bS = B + (size_t)e * KFULL * NT + (size_t)(kbase + kh * 16) * NT + n0 + bn;
    const int bD = (bn >> 4) * 512 + (kh * 2) * 128 + (bn & 15) * 8;

    f32x4 acc[4][4] = {};
    float bvA[16], bvB[16];

    unsigned short* A0 = &As[0][0];
    unsigned short* A1 = &As[1][0];
    unsigned short* A2 = &As[2][0];

#define LOADB(dst_, t_)                                                        \
    do { const float* bp_ = bS + (size_t)((t_) * 32) * NT;                     \
        _Pragma("unroll")                                                      \
        for (int i_ = 0; i_ < 16; ++i_) dst_[i_] = bp_[(size_t)i_ * NT];       \
    } while (0)

#define DMA_A(t_, abase_)                                                      \
    do { gload_lds16(aS0 + (t_) * 512, (abase_) + aD0);                        \
         gload_lds16(aS1 + (t_) * 512, (abase_) + aD1); } while (0)

#define COMMITB(src_, buf_)                                                    \
    do { uint4 q0_, q1_;                                                       \
        q0_.x = cvt_pk_bf16(src_[0],  src_[1]);  q0_.y = cvt_pk_bf16(src_[2],  src_[3]);  \
        q0_.z = cvt_pk_bf16(src_[4],  src_[5]);  q0_.w = cvt_pk_bf16(src_[6],  src_[7]);  \
        q1_.x = cvt_pk_bf16(src_[8],  src_[9]);  q1_.y = cvt_pk_bf16(src_[10], src_[11]); \
        q1_.z = cvt_pk_bf16(src_[12], src_[13]); q1_.w = cvt_pk_bf16(src_[14], src_[15]); \
        *(uint4*)&Bs[buf_][bD]       = q0_;                                    \
        *(uint4*)&Bs[buf_][bD + 128] = q1_;                                    \
    } while (0)

#define PHASE_END                                                              \
    do { asm volatile("s_waitcnt lgkmcnt(0)" ::: "memory");                    \
         __builtin_amdgcn_s_barrier();                                         \
         __builtin_amdgcn_sched_barrier(0); } while (0)

#define BODY(t_, cur_, ARD_, ADMA_, LDst_, CMsrc_, MODE_)                      \
    do {                                                                       \
        bf16x8 af_[4], bf_[4];                                                 \
        _Pragma("unroll")                                                      \
        for (int m_ = 0; m_ < 4; ++m_)                                         \
            af_[m_] = *(const bf16x8*)((ARD_) + (wr * 4 + m_) * 512 + lane * 8); \
        _Pragma("unroll")                                                      \
        for (int n_ = 0; n_ < 4; ++n_)                                         \
            bf_[n_] = *(const bf16x8*)&Bs[cur_][(wc * 4 + n_) * 512 + lane * 8]; \
        if (MODE_ == 2) DMA_A((t_) + 2, ADMA_);                                \
        if (MODE_ == 2) LOADB(LDst_, (t_) + 2);                                \
        _Pragma("unroll")                                                      \
        for (int n_ = 0; n_ < 4; ++n_)                                         \
            _Pragma("unroll")                                                  \
            for (int m_ = 0; m_ < 4; ++m_)                                     \
                acc[m_][n_] = __builtin_amdgcn_mfma_f32_16x16x32_bf16(         \
                    af_[m_], bf_[n_], acc[m_][n_], 0, 0, 0);                   \
        if (MODE_ >= 1) { COMMITB(CMsrc_, (cur_) ^ 1); PHASE_END; }            \
    } while (0)

    DMA_A(0, A0);
    LOADB(bvA, 0);
    DMA_A(1, A1);
    LOADB(bvB, 1);
    COMMITB(bvA, 0);
    PHASE_END;

#pragma unroll 1
    for (int t = 0; t + 4 <= NITER; t += 2) {
        BODY(t,     0, A0, A2, bvA, bvB, 2);
        BODY(t + 1, 1, A1, A0, bvB, bvA, 2);
        unsigned short* tr_ = A2; A2 = A1; A1 = A0; A0 = tr_;
    }
    BODY(NITER - 2, 0, A0, A2, bvA, bvB, 1);
    BODY(NITER - 1, 1, A1, A2, bvB, bvA, 0);

#undef BODY
#undef PHASE_END
#undef COMMITB
#undef DMA_A
#undef LOADB

    // epilogue: C/D layout col = lane&15 (=r), row = 4*(lane>>4) (=4g) + reg.
    // LAYER 1 writes H in BLOCKED layout (GEMM2's contiguous-DMA source).
#pragma unroll
    for (int m = 0; m < 4; ++m) {
#pragma unroll
        for (int j = 0; j < 4; ++j) {
            int lrow = mt * 128 + wr * 64 + m * 16 + g * 4 + j;
            if (lrow < ne) {
                int slot = base + lrow;
#pragma unroll
                for (int n = 0; n < 4; ++n) {
                    int col = n0 + wc * 64 + n * 16 + r;
                    if constexpr (LAYER == 1) {
                        float v = acc[m][n][j] + bias[(size_t)e * NT + col];
                        v = fmaxf(v, 0.0f);
                        H[(size_t)(slot >> 4) * XB2 + (size_t)(col >> 3) * 128
                          + (slot & 15) * 8 + (col & 7)] = f2bf(v);
                    } else {
                        atomicAdd(&out[(size_t)perm[slot] * ODIM + col],
                                  gate_s[slot] * acc[m][n][j]);
                    }
                }
            }
        }
    }
}

// ---------------- launch ----------------
extern "C" void kernel_launch(void* const* d_in, const int* in_sizes, int n_in,
                              void* d_out, int out_size, void* d_ws, size_t ws_size,
                              hipStream_t stream) {
    const float* x  = (const float*)d_in[0];
    const float* Wg = (const float*)d_in[1];
    const float* bg = (const float*)d_in[2];
    const float* W1 = (const float*)d_in[3];
    const float* b1 = (const float*)d_in[4];
    const float* W2 = (const float*)d_in[5];
    const float* b2 = (const float*)d_in[6];
    float* out = (float*)d_out;

    char* ws = (char*)d_ws;
    int*   cnt    = (int*)(ws + 0);
    int*   offs   = (int*)(ws + 64);
    int*   mc     = (int*)(ws + 128);
    int*   g1s    = (int*)(ws + 256);              // 480 ints
    int*   g2s    = (int*)(ws + 2304);             // 48 ints
    int*   tbl1   = (int*)(ws + 3072);             // 2816 ints -> ends 14336
    int*   tbl2   = (int*)(ws + 14336);            // 1344 ints -> ends 19712
    int*   top_e  = (int*)(ws + 19712);            // 4096 ints
    int*   rnk    = (int*)(ws + 19712 + 16384);    // 4096 ints
    float* top_p  = (float*)(ws + 19712 + 2 * 16384);   // 4096 f32
    int*   perm   = (int*)(ws + 68864);            // NSLOT ints
    float* gate_s = (float*)(ws + 89344);          // NSLOT f32
    unsigned short* Xg = (unsigned short*)(ws + 110592);                    // 7.86MB
    unsigned short* H  = (unsigned short*)(ws + 110592 + 320ull * XB1 * 2); // 78.6MB
    // total ws ~86.6 MB

    hipMemsetAsync(cnt, 0, NE * sizeof(int), stream);   // replaces moe_init launch
    moe_gating<<<N_TOK / 4, 256, 0, stream>>>(x, Wg, bg, cnt, top_e, rnk, top_p);
    moe_scan<<<1, 64, 0, stream>>>(cnt, offs, mc, g1s, g2s);
    moe_fill<<<(G1GRID + G2GRID + 255) / 256, 256, 0, stream>>>(mc, g1s, g2s, tbl1, tbl2);
    moe_mkperm<<<N_TOK / 256, 256, 0, stream>>>(top_e, rnk, top_p, offs, perm, gate_s);
    moe_gather<<<N_TOK, 128, 0, stream>>>(x, top_e, rnk, offs, Xg);
    moe_initout<<<N_TOK, 256, 0, stream>>>(top_e, top_p, b2, out);

    moe_gemm<1><<<G1GRID, 256, 0, stream>>>(Xg, W1, b1, cnt, offs, perm, gate_s, tbl1, H, out);
    moe_gemm<2><<<G2GRID, 256, 0, stream>>>(H, W2, b2, cnt, offs, perm, gate_s, tbl2, H, out);
}